// Round 4
// baseline (207.683 us; speedup 1.0000x reference)
//
#include <hip/hip_runtime.h>
#include <hip/hip_bf16.h>
#include <stdint.h>

#define BATCH 4
#define L_SEQ 2048
#define DIM   1024

typedef __bf16 bf16;
typedef __bf16 bf16x4 __attribute__((ext_vector_type(4)));
typedef __bf16 bf16x8 __attribute__((ext_vector_type(8)));
typedef float  f32x4  __attribute__((ext_vector_type(4)));

#define GLDS(src, dst) __builtin_amdgcn_global_load_lds(\
    (const __attribute__((address_space(1))) void*)(src), \
    (__attribute__((address_space(3))) void*)(dst), 16, 0, 0)

#define MFMA16 __builtin_amdgcn_mfma_f32_16x16x32_bf16

// ---------------- fp32 -> bf16 convert (vectorized x4) ----------------
__global__ __launch_bounds__(256)
void cvt_f32_bf16(const float* __restrict__ in, bf16* __restrict__ out, int n4)
{
    int i = blockIdx.x * 256 + threadIdx.x;
    if (i >= n4) return;
    float4 v = ((const float4*)in)[i];
    bf16x4 o = { (bf16)v.x, (bf16)v.y, (bf16)v.z, (bf16)v.w };
    ((bf16x4*)out)[i] = o;
}

// ---- 256x256-tile, BK=32, 3-buf LDS, 1 barrier + counted vmcnt per K-tile ----
// Swapped-operand convention: A-operand = the matrix whose dim is CONTIGUOUS in
// the output (MFMA D frag holds 4 consecutive M rows). A[m][k], B[n][k].
// MODE 0: QKV   A=Wcat[3072][1024], B=X[8192][1024]. sel=m0>>10: Q,K -> out[l][e] bf16x4; V -> Vt[e][l].
// MODE 2: SC    A=K[2048][1024],    B=Q[2048][1024].  out wts[q][k] f32x4 *1/32; upper tiles zero-filled.
// MODE 3: PV    A=Vt[1024][2048],   B=P[2048][2048].  out[q][e] f32x4; causal K truncation.
template<int MODE>
__global__ __launch_bounds__(512, 2)
void gemm3b(const bf16* __restrict__ Abase, const bf16* __restrict__ Bbase,
            const float* __restrict__ bqp, const float* __restrict__ bkp,
            const float* __restrict__ bvp,
            void* __restrict__ o0, void* __restrict__ o1, void* __restrict__ o2)
{
    __shared__ __align__(16) char smem[98304];   // 3 bufs x (A 16K | B 16K), rows of 64 B

    const int z = blockIdx.z;
    int m0, n0;
    const bf16 *Aop, *Bop;
    int lda, ldb, nt;

    if constexpr (MODE == 0) {
        m0 = blockIdx.x * 256; n0 = blockIdx.y * 256;
        Aop = Abase; Bop = Bbase; lda = DIM; ldb = DIM; nt = 32;
    } else if constexpr (MODE == 2) {
        const int u = blockIdx.x;
        if (u >= 36) {                            // strict-upper (k>q) tile: zeros only
            int v = u - 36;
            int mi = 1; while (mi * (mi + 1) / 2 <= v) ++mi;
            int ni = v - mi * (mi - 1) / 2;       // mi > ni
            float* sc = (float*)o0 + (size_t)z * L_SEQ * L_SEQ;
            const int row = ni * 256 + (threadIdx.x >> 1);
            float* p = sc + (size_t)row * L_SEQ + mi * 256 + (threadIdx.x & 1) * 128;
            f32x4 z4 = {0.f, 0.f, 0.f, 0.f};
#pragma unroll
            for (int c = 0; c < 32; ++c) *(f32x4*)(p + c * 4) = z4;
            return;
        }
        int ni = 0; while ((ni + 1) * (ni + 2) / 2 <= u) ++ni;
        int mi = u - ni * (ni + 1) / 2;           // mi <= ni
        m0 = mi * 256; n0 = ni * 256;
        Aop = Abase + (size_t)z * L_SEQ * DIM;    // K
        Bop = Bbase + (size_t)z * L_SEQ * DIM;    // Q
        lda = DIM; ldb = DIM; nt = 32;
    } else {
        m0 = blockIdx.x * 256; n0 = blockIdx.y * 256;
        Aop = Abase + (size_t)z * DIM * L_SEQ;    // Vt
        Bop = Bbase + (size_t)z * L_SEQ * L_SEQ;  // P
        lda = L_SEQ; ldb = L_SEQ; nt = (n0 >> 5) + 8;   // k <= n0+255
    }

    const int tid  = threadIdx.x;
    const int w    = tid >> 6, lane = tid & 63;
    const int wm   = w >> 2, wn = w & 3;          // 2 (M) x 4 (N) waves
    const int l15  = lane & 15, lh = lane >> 4;
    const int lr4  = lh << 2;

    f32x4 acc[8][4];
#pragma unroll
    for (int i = 0; i < 8; ++i)
#pragma unroll
        for (int j = 0; j < 4; ++j) acc[i][j] = (f32x4){0.f, 0.f, 0.f, 0.f};

    // staging: [256 rows][32 cols] bf16 = 64 B/row, linear. 4 GLDS/wave/tile.
    const int rA = lane >> 2;                     // 0..15
    const int cA = (lane & 3) << 3;               // element col 0,8,16,24

    auto stage = [&](char* buf, int kt) {
        const int k0 = kt << 5;
        GLDS(Aop + (size_t)(m0 + w * 32 + rA)      * lda + (k0 + cA), buf + w * 2048);
        GLDS(Aop + (size_t)(m0 + w * 32 + 16 + rA) * lda + (k0 + cA), buf + w * 2048 + 1024);
        GLDS(Bop + (size_t)(n0 + w * 32 + rA)      * ldb + (k0 + cA), buf + 16384 + w * 2048);
        GLDS(Bop + (size_t)(n0 + w * 32 + 16 + rA) * ldb + (k0 + cA), buf + 16384 + w * 2048 + 1024);
    };

    char* pc = smem;                              // compute buffer
    char* pn = smem + 32768;                      // stage target (t+1)
    char* pl = smem + 65536;                      // retired

    stage(pc, 0);
    for (int t = 0; t < nt; ++t) {
        if (t + 1 < nt) {
            stage(pn, t + 1);
            asm volatile("s_waitcnt vmcnt(4)" ::: "memory");  // tile t resident; t+1 in flight
        } else {
            asm volatile("s_waitcnt vmcnt(0)" ::: "memory");
        }
        __builtin_amdgcn_s_barrier();
        __builtin_amdgcn_sched_barrier(0);

        bf16x8 af[8], bfr[4];
#pragma unroll
        for (int i = 0; i < 8; ++i)
            af[i] = *(const bf16x8*)(pc + (wm * 128 + i * 16 + l15) * 64 + (lh << 4));
#pragma unroll
        for (int j = 0; j < 4; ++j)
            bfr[j] = *(const bf16x8*)(pc + 16384 + (wn * 64 + j * 16 + l15) * 64 + (lh << 4));

        __builtin_amdgcn_s_setprio(1);
#pragma unroll
        for (int i = 0; i < 8; ++i)
#pragma unroll
            for (int j = 0; j < 4; ++j)
                acc[i][j] = MFMA16(af[i], bfr[j], acc[i][j], 0, 0, 0);
        __builtin_amdgcn_s_setprio(0);

        char* tmp = pc; pc = pn; pn = pl; pl = tmp;
    }

    // ---- epilogue: D frag = 4 consecutive M rows (lh*4+r), N col = l15 ----
    if constexpr (MODE == 0) {
        const int sel = m0 >> 10;                 // 0:Q 1:K 2:V (uniform per block)
        const int eb  = (m0 & 1023) + wm * 128;
        if (sel < 2) {
            bf16* out = sel == 0 ? (bf16*)o0 : (bf16*)o1;
            const float* bias = sel == 0 ? bqp : bkp;
#pragma unroll
            for (int i = 0; i < 8; ++i) {
                int e0 = eb + i * 16 + lr4;
                float4 bb = *(const float4*)(bias + e0);
#pragma unroll
                for (int j = 0; j < 4; ++j) {
                    int l = n0 + wn * 64 + j * 16 + l15;
                    bf16x4 v = { (bf16)(acc[i][j][0] + bb.x), (bf16)(acc[i][j][1] + bb.y),
                                 (bf16)(acc[i][j][2] + bb.z), (bf16)(acc[i][j][3] + bb.w) };
                    *(bf16x4*)((bf16*)out + (size_t)l * DIM + e0) = v;
                }
            }
        } else {
            bf16* Vt = (bf16*)o2;
#pragma unroll
            for (int i = 0; i < 8; ++i) {
                int e0 = eb + i * 16 + lr4;
                float4 bb = *(const float4*)(bvp + e0);
                float bbr[4] = { bb.x, bb.y, bb.z, bb.w };
#pragma unroll
                for (int j = 0; j < 4; ++j) {
                    int lg = n0 + wn * 64 + j * 16 + l15;
                    int b = lg >> 11, l = lg & 2047;
#pragma unroll
                    for (int r = 0; r < 4; ++r)
                        Vt[((size_t)b * DIM + e0 + r) * L_SEQ + l] = (bf16)(acc[i][j][r] + bbr[r]);
                }
            }
        }
    } else if constexpr (MODE == 2) {
        float* sc = (float*)o0 + (size_t)z * L_SEQ * L_SEQ;
#pragma unroll
        for (int i = 0; i < 8; ++i) {
            int k0e = m0 + wm * 128 + i * 16 + lr4;
#pragma unroll
            for (int j = 0; j < 4; ++j) {
                int q = n0 + wn * 64 + j * 16 + l15;
                f32x4 v = acc[i][j] * 0.03125f;
                *(f32x4*)(sc + (size_t)q * L_SEQ + k0e) = v;
            }
        }
    } else {
        float* o = (float*)o0 + (size_t)z * L_SEQ * DIM;
#pragma unroll
        for (int i = 0; i < 8; ++i) {
            int e0 = m0 + wm * 128 + i * 16 + lr4;
#pragma unroll
            for (int j = 0; j < 4; ++j) {
                int q = n0 + wn * 64 + j * 16 + l15;
                *(f32x4*)(o + (size_t)q * DIM + e0) = acc[i][j];
            }
        }
    }
}

// ---------------- causal row softmax: wts fp32 (in-place) + bf16 copy ----------------
// upper-triangle tiles of wts are pre-zeroed by SC; store only k0 <= (q|255).
__global__ __launch_bounds__(256)
void softmax_rows(float* __restrict__ wts, bf16* __restrict__ Pb)
{
    const int row = blockIdx.x;                 // 0..8191
    const int q = row & 2047;
    float* s = wts + (size_t)row * L_SEQ;
    bf16*  p = Pb  + (size_t)row * L_SEQ;
    const int t = threadIdx.x;
    const int lane = t & 63, w = t >> 6;
    const int k0 = t * 8;

    float v[8];
    if (k0 + 7 <= q) {
        float4 a = *(const float4*)(s + k0);
        float4 b = *(const float4*)(s + k0 + 4);
        v[0]=a.x; v[1]=a.y; v[2]=a.z; v[3]=a.w;
        v[4]=b.x; v[5]=b.y; v[6]=b.z; v[7]=b.w;
    } else {
#pragma unroll
        for (int c = 0; c < 8; ++c) {
            int k = k0 + c;
            v[c] = (k <= q) ? s[k] : -3.0e38f;
        }
    }

    float mx = v[0];
#pragma unroll
    for (int c = 1; c < 8; ++c) mx = fmaxf(mx, v[c]);
#pragma unroll
    for (int off = 32; off; off >>= 1) mx = fmaxf(mx, __shfl_xor(mx, off));
    __shared__ float redm[4];
    if (lane == 0) redm[w] = mx;
    __syncthreads();
    mx = fmaxf(fmaxf(redm[0], redm[1]), fmaxf(redm[2], redm[3]));

    float sm = 0.f;
#pragma unroll
    for (int c = 0; c < 8; ++c) {
        float e = __expf(v[c] - mx);             // masked -> 0 exactly
        v[c] = e;
        sm += e;
    }
#pragma unroll
    for (int off = 32; off; off >>= 1) sm += __shfl_xor(sm, off);
    __shared__ float reds[4];
    if (lane == 0) reds[w] = sm;
    __syncthreads();
    sm = reds[0] + reds[1] + reds[2] + reds[3];
    const float inv = 1.f / sm;

    if (k0 <= (q | 255)) {                       // beyond diag tile: pre-zeroed, PV never reads
        float o[8];
#pragma unroll
        for (int c = 0; c < 8; ++c) o[c] = v[c] * inv;
        float4 s0 = { o[0], o[1], o[2], o[3] };
        float4 s1 = { o[4], o[5], o[6], o[7] };
        *(float4*)(s + k0)     = s0;
        *(float4*)(s + k0 + 4) = s1;
        bf16x8 pb = { (bf16)o[0], (bf16)o[1], (bf16)o[2], (bf16)o[3],
                      (bf16)o[4], (bf16)o[5], (bf16)o[6], (bf16)o[7] };
        *(bf16x8*)(p + k0) = pb;
    }
}

extern "C" void kernel_launch(void* const* d_in, const int* in_sizes, int n_in,
                              void* d_out, int out_size, void* d_ws, size_t ws_size,
                              hipStream_t stream)
{
    const float* x  = (const float*)d_in[0];
    const float* Wq = (const float*)d_in[1];
    const float* bq = (const float*)d_in[2];
    const float* Wk = (const float*)d_in[3];
    const float* bk = (const float*)d_in[4];
    const float* Wv = (const float*)d_in[5];
    const float* bv = (const float*)d_in[6];

    float* out = (float*)d_out;                               // [4][2048][1024]
    float* wts = out + (size_t)BATCH * L_SEQ * DIM;           // [4][2048][2048]

    char* ws = (char*)d_ws;
    bf16* Xb   = (bf16*)(ws + 0);                  // 16 MiB  [8192][1024]
    bf16* Wcat = (bf16*)(ws + (16u  << 20));       //  6 MiB  [3072][1024]  (Wq;Wk;Wv)
    bf16* Qb   = (bf16*)(ws + (22u  << 20));       // 16 MiB  [b][l][e]
    bf16* Kb   = (bf16*)(ws + (38u  << 20));       // 16 MiB  [b][l][e]
    bf16* Vt   = (bf16*)(ws + (54u  << 20));       // 16 MiB  [b][e][l]
    bf16* Pb   = (bf16*)(ws + (70u  << 20));       // 32 MiB  [b][q][k]

    cvt_f32_bf16<<<dim3(8192), dim3(256), 0, stream>>>(x,  Xb, 8388608 / 4);
    cvt_f32_bf16<<<dim3(1024), dim3(256), 0, stream>>>(Wq, Wcat,           1048576 / 4);
    cvt_f32_bf16<<<dim3(1024), dim3(256), 0, stream>>>(Wk, Wcat + 1048576, 1048576 / 4);
    cvt_f32_bf16<<<dim3(1024), dim3(256), 0, stream>>>(Wv, Wcat + 2097152, 1048576 / 4);

    gemm3b<0><<<dim3(12, 32, 1), dim3(512), 0, stream>>>(Wcat, Xb, bq, bk, bv, Qb, Kb, Vt);
    gemm3b<2><<<dim3(64, 1, 4),  dim3(512), 0, stream>>>(Kb, Qb, nullptr, nullptr, nullptr, wts, nullptr, nullptr);
    softmax_rows<<<dim3(8192), dim3(256), 0, stream>>>(wts, Pb);
    gemm3b<3><<<dim3(4, 8, 4),   dim3(512), 0, stream>>>(Vt, Pb, nullptr, nullptr, nullptr, out, nullptr, nullptr);
}